// Round 4
// baseline (536.032 us; speedup 1.0000x reference)
//
#include <hip/hip_runtime.h>
#include <hip/hip_cooperative_groups.h>
#include <math.h>

namespace cg = cooperative_groups;

#define IN_NUM 1152
#define IN_DIM 8
#define OUT_NUM 10
#define OUT_DIM 16
#define BATCH 256
#define KTOT 9216            // IN_DIM * IN_NUM; k = d*IN_NUM + i
#define WJ 147456            // 16 * 9216, per-j Wo/Wc stride
#define GRID 512

typedef __attribute__((ext_vector_type(8))) short short8;
typedef __attribute__((ext_vector_type(4))) short short4v;
typedef __attribute__((ext_vector_type(4))) float f32x4;

__device__ __forceinline__ unsigned short f2bf(float f) {
    unsigned int u = __builtin_bit_cast(unsigned int, f);
    u += 0x7FFF + ((u >> 16) & 1);          // RNE
    return (unsigned short)(u >> 16);
}
__device__ __forceinline__ float bf2f(unsigned short h) {
    unsigned int u = ((unsigned int)h) << 16;
    return __builtin_bit_cast(float, u);
}

// ---- phase S: GEMM-s + squash. blocks [0,160) = (j, btile). 4 waves split K.
__device__ __forceinline__ void phase_S(const unsigned short* __restrict__ A,
                                        const unsigned short* __restrict__ xb,
                                        unsigned short* __restrict__ vb,
                                        float* __restrict__ out,
                                        float scale, int wout, float* LS) {
    if (blockIdx.x >= 160) return;
    const int j     = blockIdx.x >> 4;
    const int btile = blockIdx.x & 15;
    const int w    = threadIdx.x >> 6;
    const int lane = threadIdx.x & 63;
    const int row = lane & 15, kg = lane >> 4;

    const unsigned short* ap = A  + (size_t)j * WJ + row * KTOT + w * 2304 + kg * 8;
    const unsigned short* bp = xb + (size_t)(btile * 16 + row) * KTOT + w * 2304 + kg * 8;

    f32x4 acc = {0.f, 0.f, 0.f, 0.f};
    #pragma unroll 8
    for (int it = 0; it < 72; ++it) {        // 72 * 32 = 2304 k per wave
        short8 a = *reinterpret_cast<const short8*>(ap);
        short8 b = *reinterpret_cast<const short8*>(bp);
        acc = __builtin_amdgcn_mfma_f32_16x16x32_bf16(a, b, acc, 0, 0, 0);
        ap += 32; bp += 32;
    }
    // D: col(lane&15) -> b, row kg*4+r -> o.  Sred[w][o][b] = LS[w*256+o*16+b]
    #pragma unroll
    for (int r = 0; r < 4; ++r) LS[w * 256 + (kg * 4 + r) * 16 + row] = acc[r];
    __syncthreads();

    const int o = threadIdx.x >> 4, b = threadIdx.x & 15;
    float sum = LS[0 * 256 + o * 16 + b] + LS[1 * 256 + o * 16 + b]
              + LS[2 * 256 + o * 16 + b] + LS[3 * 256 + o * 16 + b];
    __syncthreads();
    LS[o * 16 + b] = sum;                    // own slot
    __syncthreads();
    float m2r = 0.f;
    #pragma unroll
    for (int oo = 0; oo < 16; ++oo) { const float q = LS[oo * 16 + b]; m2r += q * q; }
    const float m2 = m2r * scale * scale;
    const float f  = sqrtf(m2) / (1.0f + m2);
    vb[(size_t)j * OUT_DIM * BATCH + o * BATCH + btile * 16 + b] = f2bf(sum * scale * f);
    if (wout) {
        if (o == 0) LS[1024 + b] = f;        // fs[b]
        __syncthreads();
        const int b2 = threadIdx.x >> 4, o2 = threadIdx.x & 15;
        out[((size_t)j * BATCH + btile * 16 + b2) * OUT_DIM + o2] =
            LS[o2 * 16 + b2] * scale * LS[1024 + b2];   // coalesced f32
    }
}

// ---- phase G: GEMM-G + b-partials. 5760 wave units over 2048 wave slots.
__device__ __forceinline__ void phase_G(const unsigned short* __restrict__ xT,
                                        const unsigned short* __restrict__ vb,
                                        const unsigned short* __restrict__ Wo,
                                        float* __restrict__ bpd) {
    const int w    = threadIdx.x >> 6;
    const int lane = threadIdx.x & 63;
    const int rc = lane & 15, kg = lane >> 4;
    for (int base = 0; base < 5760; base += GRID * 4) {
        const int wid = base + blockIdx.x * 4 + w;
        if (wid >= 5760) break;
        const int j  = wid % 10;
        const int kt = wid / 10;             // < 576

        const unsigned short* ap = xT + (size_t)(kt * 16 + rc) * BATCH + kg * 8;
        const unsigned short* vp = vb + (size_t)j * OUT_DIM * BATCH + rc * BATCH + kg * 8;

        f32x4 acc = {0.f, 0.f, 0.f, 0.f};
        #pragma unroll
        for (int bb = 0; bb < 8; ++bb) {     // 8 * 32 = 256 = BATCH
            short8 a = *reinterpret_cast<const short8*>(ap + bb * 32);
            short8 b = *reinterpret_cast<const short8*>(vp + bb * 32);
            acc = __builtin_amdgcn_mfma_f32_16x16x32_bf16(a, b, acc, 0, 0, 0);
        }
        // lane(rc,kg) holds G[k = kt*16 + kg*4 + r][o = rc]
        const int kbase = kt * 16 + kg * 4;
        short4v w4 = *reinterpret_cast<const short4v*>(
            Wo + (size_t)j * WJ + rc * KTOT + kbase);
        float p[4];
        #pragma unroll
        for (int r = 0; r < 4; ++r) p[r] = acc[r] * bf2f((unsigned short)w4[r]);
        #pragma unroll
        for (int m = 1; m < 16; m <<= 1) {
            #pragma unroll
            for (int r = 0; r < 4; ++r) p[r] += __shfl_xor(p[r], m);
        }
        if (rc == 0) {
            float4 v4 = make_float4(p[0], p[1], p[2], p[3]);
            *reinterpret_cast<float4*>(bpd + (size_t)j * KTOT + kbase) = v4;
        }
    }
}

// ---- phase CW: fused softmax(from bp partials) + Wc = c * Wo.
// blocks [0,180) = (j0, 64-wide i stripe). Logits cumulative over bp0(+bp1).
__device__ __forceinline__ void phase_CW(const float* __restrict__ bp0,
                                         const float* __restrict__ bp1,
                                         const unsigned short* __restrict__ Wo,
                                         unsigned short* __restrict__ Wc,
                                         float* LS) {
    if (blockIdx.x >= 180) return;
    const int j0 = blockIdx.x / 18;
    const int i0 = (blockIdx.x % 18) * 64;
    const int t = threadIdx.x;
    if (t < 64) {
        const int i = i0 + t;
        float lg[OUT_NUM];
        float m = -INFINITY;
        #pragma unroll
        for (int j = 0; j < OUT_NUM; ++j) {
            float s = 0.f;
            #pragma unroll
            for (int d = 0; d < IN_DIM; ++d) {
                s += bp0[(size_t)j * KTOT + d * IN_NUM + i];
                if (bp1) s += bp1[(size_t)j * KTOT + d * IN_NUM + i];
            }
            lg[j] = s * (1.0f / BATCH);
            m = fmaxf(m, lg[j]);
        }
        float den = 0.f;
        #pragma unroll
        for (int j = 0; j < OUT_NUM; ++j) den += expf(lg[j] - m);
        LS[t] = expf(lg[j0] - m) / den;      // cs[il]
    }
    __syncthreads();
    #pragma unroll
    for (int q = 0; q < 4; ++q) {
        const int ev = t + 256 * q;          // vector-of-8 index, 1024 total
        const int od = ev >> 3;              // 0..127
        const int il = (ev & 7) * 8;
        const int o = od >> 3, d = od & 7;
        const size_t idx = (size_t)j0 * WJ + o * KTOT + d * IN_NUM + i0 + il;
        short8 wv = *reinterpret_cast<const short8*>(Wo + idx);
        unsigned short ov[8];
        #pragma unroll
        for (int e = 0; e < 8; ++e)
            ov[e] = f2bf(bf2f((unsigned short)wv[e]) * LS[il + e]);
        *reinterpret_cast<short8*>(Wc + idx) = *reinterpret_cast<const short8*>(ov);
    }
}

// ---------------------------------------------------------------------------
__global__ __launch_bounds__(256, 2) void k_all(const float* __restrict__ W,
                                                const float* __restrict__ x,
                                                float* __restrict__ out,
                                                unsigned short* __restrict__ Wo,
                                                unsigned short* __restrict__ Wc,
                                                unsigned short* __restrict__ xb,
                                                unsigned short* __restrict__ xT,
                                                unsigned short* __restrict__ vb,
                                                float* __restrict__ bp0,
                                                float* __restrict__ bp1) {
    __shared__ float LS[8320];               // 33.3 KB, unioned across phases
    cg::grid_group grid = cg::this_grid();
    const int t = threadIdx.x;

    // ---- P: prep. units [0,180): W -> Wo bf16; [180,756): x -> xb, xT bf16
    for (int unit = blockIdx.x; unit < 756; unit += GRID) {
        if (unit < 180) {
            const int j  = unit / 18;
            const int i0 = (unit % 18) * 64;
            #pragma unroll 4
            for (int st = 0; st < 32; ++st) {
                const int il = st * 2 + (t >> 7);
                const int od = t & 127;
                LS[il * 130 + od] = W[(size_t)(i0 + il) * 1280 + j * 128 + od];
            }
            __syncthreads();
            #pragma unroll 4
            for (int st = 0; st < 32; ++st) {
                const int od = st * 4 + (t >> 6);
                const int il = t & 63;
                const int o = od >> 3, d = od & 7;
                Wo[(size_t)j * WJ + o * KTOT + d * IN_NUM + i0 + il] = f2bf(LS[il * 130 + od]);
            }
        } else {
            const int bx = unit - 180;
            const int k0 = (bx >> 2) * 64;
            const int b0 = (bx & 3) * 64;
            #pragma unroll 4
            for (int st = 0; st < 16; ++st) {
                const int bl = st * 4 + (t >> 6);
                const int kl = t & 63;
                const float f = x[(size_t)(b0 + bl) * KTOT + k0 + kl];
                LS[kl * 65 + bl] = f;
                xb[(size_t)(b0 + bl) * KTOT + k0 + kl] = f2bf(f);
            }
            __syncthreads();
            #pragma unroll 4
            for (int st = 0; st < 16; ++st) {
                const int kl = st * 4 + (t >> 6);
                const int bl = t & 63;
                xT[(size_t)(k0 + kl) * BATCH + b0 + bl] = f2bf(LS[kl * 65 + bl]);
            }
        }
        __syncthreads();
    }
    grid.sync();
    // iter 0 (c uniform 0.1 folded into squash scale)
    phase_S(Wo, xb, vb, out, 0.1f, 0, LS);
    grid.sync();
    phase_G(xT, vb, Wo, bp0);
    grid.sync();
    // iter 1
    phase_CW(bp0, nullptr, Wo, Wc, LS);
    grid.sync();
    phase_S(Wc, xb, vb, out, 1.0f, 0, LS);
    grid.sync();
    phase_G(xT, vb, Wo, bp1);
    grid.sync();
    // iter 2 (final)
    phase_CW(bp0, bp1, Wo, Wc, LS);
    grid.sync();
    phase_S(Wc, xb, vb, out, 1.0f, 1, LS);
}

// ---------------------------------------------------------------------------
extern "C" void kernel_launch(void* const* d_in, const int* in_sizes, int n_in,
                              void* d_out, int out_size, void* d_ws, size_t ws_size,
                              hipStream_t stream) {
    const float* x = (const float*)d_in[0];   // [256][8][1152]
    const float* W = (const float*)d_in[1];   // [1152][10][16][8]
    float* out = (float*)d_out;               // [10][256][16]
    float* ws = (float*)d_ws;

    float*          bp0 = ws;                                  // 92160 f32
    float*          bp1 = ws + 92160;                          // 92160 f32
    unsigned short* vb  = (unsigned short*)(ws + 184320);      // 40960 bf16
    unsigned short* Wo  = (unsigned short*)(ws + 204800);      // 1474560 bf16
    unsigned short* Wc  = (unsigned short*)(ws + 942080);      // 1474560 bf16
    unsigned short* xb  = (unsigned short*)(ws + 1679360);     // 2359296 bf16
    unsigned short* xT  = (unsigned short*)(ws + 2859008);     // 2359296 bf16
    // end: 4038656 f32 = 16.2 MB

    void* args[] = {(void*)&W, (void*)&x, (void*)&out, (void*)&Wo, (void*)&Wc,
                    (void*)&xb, (void*)&xT, (void*)&vb, (void*)&bp0, (void*)&bp1};
    hipLaunchCooperativeKernel((const void*)k_all, dim3(GRID), dim3(256),
                               args, 0, stream);
}

// Round 5
// 390.959 us; speedup vs baseline: 1.3711x; 1.3711x over previous
//
#include <hip/hip_runtime.h>
#include <math.h>

#define IN_NUM 1152
#define IN_DIM 8
#define OUT_NUM 10
#define OUT_DIM 16
#define BATCH 256
#define KTOT 9216            // IN_DIM * IN_NUM; k = d*IN_NUM + i
#define WJ 147456            // 16 * 9216, per-j Wo/Wc stride
#define GRID 256

typedef __attribute__((ext_vector_type(8))) short short8;
typedef __attribute__((ext_vector_type(4))) short short4v;
typedef __attribute__((ext_vector_type(4))) float f32x4;

__device__ __forceinline__ unsigned short f2bf(float f) {
    unsigned int u = __builtin_bit_cast(unsigned int, f);
    u += 0x7FFF + ((u >> 16) & 1);          // RNE
    return (unsigned short)(u >> 16);
}
__device__ __forceinline__ float bf2f(unsigned short h) {
    unsigned int u = ((unsigned int)h) << 16;
    return __builtin_bit_cast(float, u);
}

// ---- two-level grid barrier, monotonic epochs (no reset, poison-safe via memset).
// bar[l*32] l<16 : leaf counters (128B apart); bar[512]: root; bar[544]: release flag.
__device__ __forceinline__ void gbar(unsigned int* bar, unsigned int epoch) {
    __syncthreads();
    if (threadIdx.x == 0) {
        const int l = blockIdx.x & 15;
        unsigned int old = __hip_atomic_fetch_add(&bar[l * 32], 1u,
                               __ATOMIC_ACQ_REL, __HIP_MEMORY_SCOPE_AGENT);
        if ((old & 15u) == 15u) {            // 16th arrival at this leaf this epoch
            unsigned int r = __hip_atomic_fetch_add(&bar[512], 1u,
                               __ATOMIC_ACQ_REL, __HIP_MEMORY_SCOPE_AGENT);
            if ((r & 15u) == 15u)            // 16th leaf -> release
                __hip_atomic_fetch_add(&bar[544], 1u,
                               __ATOMIC_RELEASE, __HIP_MEMORY_SCOPE_AGENT);
        }
        while (__hip_atomic_load(&bar[544], __ATOMIC_ACQUIRE,
                                 __HIP_MEMORY_SCOPE_AGENT) < epoch)
            __builtin_amdgcn_s_sleep(2);     // ~128 cycles
    }
    __syncthreads();
}

// ---- phase S: GEMM-s + squash. blocks [0,160) = (j, btile). 4 waves split K.
__device__ __forceinline__ void phase_S(const unsigned short* __restrict__ A,
                                        const unsigned short* __restrict__ xb,
                                        unsigned short* __restrict__ vb,
                                        float* __restrict__ out,
                                        float scale, int wout, float* LS) {
    if (blockIdx.x >= 160) return;
    const int j     = blockIdx.x >> 4;
    const int btile = blockIdx.x & 15;
    const int w    = threadIdx.x >> 6;
    const int lane = threadIdx.x & 63;
    const int row = lane & 15, kg = lane >> 4;

    const unsigned short* ap = A  + (size_t)j * WJ + row * KTOT + w * 2304 + kg * 8;
    const unsigned short* bp = xb + (size_t)(btile * 16 + row) * KTOT + w * 2304 + kg * 8;

    f32x4 acc0 = {0.f, 0.f, 0.f, 0.f}, acc1 = {0.f, 0.f, 0.f, 0.f};
    #pragma unroll 4
    for (int it = 0; it < 36; ++it) {        // 36 * 64 = 2304 k per wave, dual acc
        short8 a0 = *reinterpret_cast<const short8*>(ap);
        short8 b0 = *reinterpret_cast<const short8*>(bp);
        acc0 = __builtin_amdgcn_mfma_f32_16x16x32_bf16(a0, b0, acc0, 0, 0, 0);
        short8 a1 = *reinterpret_cast<const short8*>(ap + 32);
        short8 b1 = *reinterpret_cast<const short8*>(bp + 32);
        acc1 = __builtin_amdgcn_mfma_f32_16x16x32_bf16(a1, b1, acc1, 0, 0, 0);
        ap += 64; bp += 64;
    }
    f32x4 acc = acc0 + acc1;
    // D: col(lane&15) -> b, row kg*4+r -> o.  Sred[w][o][b] = LS[w*256+o*16+b]
    #pragma unroll
    for (int r = 0; r < 4; ++r) LS[w * 256 + (kg * 4 + r) * 16 + row] = acc[r];
    __syncthreads();

    const int o = threadIdx.x >> 4, b = threadIdx.x & 15;
    float sum = LS[0 * 256 + o * 16 + b] + LS[1 * 256 + o * 16 + b]
              + LS[2 * 256 + o * 16 + b] + LS[3 * 256 + o * 16 + b];
    __syncthreads();
    LS[o * 16 + b] = sum;                    // own slot
    __syncthreads();
    float m2r = 0.f;
    #pragma unroll
    for (int oo = 0; oo < 16; ++oo) { const float q = LS[oo * 16 + b]; m2r += q * q; }
    const float m2 = m2r * scale * scale;
    const float f  = sqrtf(m2) / (1.0f + m2);
    vb[(size_t)j * OUT_DIM * BATCH + o * BATCH + btile * 16 + b] = f2bf(sum * scale * f);
    if (wout) {
        if (o == 0) LS[1024 + b] = f;        // fs[b]
        __syncthreads();
        const int b2 = threadIdx.x >> 4, o2 = threadIdx.x & 15;
        out[((size_t)j * BATCH + btile * 16 + b2) * OUT_DIM + o2] =
            LS[o2 * 16 + b2] * scale * LS[1024 + b2];   // coalesced f32
    }
}

// ---- phase G: GEMM-G + b-partials. 5760 wave units grid-strided over GRID*4.
__device__ __forceinline__ void phase_G(const unsigned short* __restrict__ xT,
                                        const unsigned short* __restrict__ vb,
                                        const unsigned short* __restrict__ Wo,
                                        float* __restrict__ bpd) {
    const int w    = threadIdx.x >> 6;
    const int lane = threadIdx.x & 63;
    const int rc = lane & 15, kg = lane >> 4;
    for (int base = 0; base < 5760; base += GRID * 4) {
        const int wid = base + blockIdx.x * 4 + w;
        if (wid >= 5760) break;
        const int j  = wid % 10;
        const int kt = wid / 10;             // < 576

        const unsigned short* ap = xT + (size_t)(kt * 16 + rc) * BATCH + kg * 8;
        const unsigned short* vp = vb + (size_t)j * OUT_DIM * BATCH + rc * BATCH + kg * 8;

        f32x4 acc0 = {0.f, 0.f, 0.f, 0.f}, acc1 = {0.f, 0.f, 0.f, 0.f};
        #pragma unroll
        for (int bb = 0; bb < 4; ++bb) {     // 4 * 64 = 256 = BATCH, dual acc
            short8 a0 = *reinterpret_cast<const short8*>(ap + bb * 64);
            short8 b0 = *reinterpret_cast<const short8*>(vp + bb * 64);
            acc0 = __builtin_amdgcn_mfma_f32_16x16x32_bf16(a0, b0, acc0, 0, 0, 0);
            short8 a1 = *reinterpret_cast<const short8*>(ap + bb * 64 + 32);
            short8 b1 = *reinterpret_cast<const short8*>(vp + bb * 64 + 32);
            acc1 = __builtin_amdgcn_mfma_f32_16x16x32_bf16(a1, b1, acc1, 0, 0, 0);
        }
        f32x4 acc = acc0 + acc1;
        // lane(rc,kg) holds G[k = kt*16 + kg*4 + r][o = rc]
        const int kbase = kt * 16 + kg * 4;
        short4v w4 = *reinterpret_cast<const short4v*>(
            Wo + (size_t)j * WJ + rc * KTOT + kbase);
        float p[4];
        #pragma unroll
        for (int r = 0; r < 4; ++r) p[r] = acc[r] * bf2f((unsigned short)w4[r]);
        #pragma unroll
        for (int m = 1; m < 16; m <<= 1) {
            #pragma unroll
            for (int r = 0; r < 4; ++r) p[r] += __shfl_xor(p[r], m);
        }
        if (rc == 0) {
            float4 v4 = make_float4(p[0], p[1], p[2], p[3]);
            *reinterpret_cast<float4*>(bpd + (size_t)j * KTOT + kbase) = v4;
        }
    }
}

// ---- phase CW: fused softmax(from bp partials) + Wc = c * Wo. blocks [0,180).
__device__ __forceinline__ void phase_CW(const float* __restrict__ bp0,
                                         const float* __restrict__ bp1,
                                         const unsigned short* __restrict__ Wo,
                                         unsigned short* __restrict__ Wc,
                                         float* LS) {
    if (blockIdx.x >= 180) return;
    const int j0 = blockIdx.x / 18;
    const int i0 = (blockIdx.x % 18) * 64;
    const int t = threadIdx.x;
    if (t < 64) {
        const int i = i0 + t;
        float lg[OUT_NUM];
        float m = -INFINITY;
        #pragma unroll
        for (int j = 0; j < OUT_NUM; ++j) {
            float s = 0.f;
            #pragma unroll
            for (int d = 0; d < IN_DIM; ++d) {
                s += bp0[(size_t)j * KTOT + d * IN_NUM + i];
                if (bp1) s += bp1[(size_t)j * KTOT + d * IN_NUM + i];
            }
            lg[j] = s * (1.0f / BATCH);
            m = fmaxf(m, lg[j]);
        }
        float den = 0.f;
        #pragma unroll
        for (int j = 0; j < OUT_NUM; ++j) den += expf(lg[j] - m);
        LS[t] = expf(lg[j0] - m) / den;      // cs[il]
    }
    __syncthreads();
    #pragma unroll
    for (int q = 0; q < 4; ++q) {
        const int ev = t + 256 * q;          // vector-of-8 index, 1024 total
        const int od = ev >> 3;              // 0..127
        const int il = (ev & 7) * 8;
        const int o = od >> 3, d = od & 7;
        const size_t idx = (size_t)j0 * WJ + o * KTOT + d * IN_NUM + i0 + il;
        short8 wv = *reinterpret_cast<const short8*>(Wo + idx);
        unsigned short ov[8];
        #pragma unroll
        for (int e = 0; e < 8; ++e)
            ov[e] = f2bf(bf2f((unsigned short)wv[e]) * LS[il + e]);
        *reinterpret_cast<short8*>(Wc + idx) = *reinterpret_cast<const short8*>(ov);
    }
}

// ---------------------------------------------------------------------------
__global__ __launch_bounds__(256, 2) void k_all(const float* __restrict__ W,
                                                const float* __restrict__ x,
                                                float* __restrict__ out,
                                                unsigned short* __restrict__ Wo,
                                                unsigned short* __restrict__ Wc,
                                                unsigned short* __restrict__ xb,
                                                unsigned short* __restrict__ xT,
                                                unsigned short* __restrict__ vb,
                                                float* __restrict__ bp0,
                                                float* __restrict__ bp1,
                                                unsigned int* bar) {
    __shared__ float LS[8320];               // 33.3 KB, unioned across phases
    const int t = threadIdx.x;

    // ---- P: prep. units [0,180): W -> Wo bf16; [180,756): x -> xb, xT bf16
    for (int unit = blockIdx.x; unit < 756; unit += GRID) {
        if (unit < 180) {
            const int j  = unit / 18;
            const int i0 = (unit % 18) * 64;
            #pragma unroll 4
            for (int st = 0; st < 32; ++st) {
                const int il = st * 2 + (t >> 7);
                const int od = t & 127;
                LS[il * 130 + od] = W[(size_t)(i0 + il) * 1280 + j * 128 + od];
            }
            __syncthreads();
            #pragma unroll 4
            for (int st = 0; st < 32; ++st) {
                const int od = st * 4 + (t >> 6);
                const int il = t & 63;
                const int o = od >> 3, d = od & 7;
                Wo[(size_t)j * WJ + o * KTOT + d * IN_NUM + i0 + il] = f2bf(LS[il * 130 + od]);
            }
        } else {
            const int bx = unit - 180;
            const int k0 = (bx >> 2) * 64;
            const int b0 = (bx & 3) * 64;
            #pragma unroll 4
            for (int st = 0; st < 16; ++st) {
                const int bl = st * 4 + (t >> 6);
                const int kl = t & 63;
                const float f = x[(size_t)(b0 + bl) * KTOT + k0 + kl];
                LS[kl * 65 + bl] = f;
                xb[(size_t)(b0 + bl) * KTOT + k0 + kl] = f2bf(f);
            }
            __syncthreads();
            #pragma unroll 4
            for (int st = 0; st < 16; ++st) {
                const int kl = st * 4 + (t >> 6);
                const int bl = t & 63;
                xT[(size_t)(k0 + kl) * BATCH + b0 + bl] = f2bf(LS[kl * 65 + bl]);
            }
        }
        __syncthreads();
    }
    gbar(bar, 1);
    // iter 0 (c uniform 0.1 folded into squash scale)
    phase_S(Wo, xb, vb, out, 0.1f, 0, LS);
    gbar(bar, 2);
    phase_G(xT, vb, Wo, bp0);
    gbar(bar, 3);
    // iter 1
    phase_CW(bp0, nullptr, Wo, Wc, LS);
    gbar(bar, 4);
    phase_S(Wc, xb, vb, out, 1.0f, 0, LS);
    gbar(bar, 5);
    phase_G(xT, vb, Wo, bp1);
    gbar(bar, 6);
    // iter 2 (final)
    phase_CW(bp0, bp1, Wo, Wc, LS);
    gbar(bar, 7);
    phase_S(Wc, xb, vb, out, 1.0f, 1, LS);
}

// ---------------------------------------------------------------------------
extern "C" void kernel_launch(void* const* d_in, const int* in_sizes, int n_in,
                              void* d_out, int out_size, void* d_ws, size_t ws_size,
                              hipStream_t stream) {
    const float* x = (const float*)d_in[0];   // [256][8][1152]
    const float* W = (const float*)d_in[1];   // [1152][10][16][8]
    float* out = (float*)d_out;               // [10][256][16]
    float* ws = (float*)d_ws;

    unsigned int*   bar = (unsigned int*)ws;                   // 576 u32 (barrier)
    float*          bp0 = ws + 576;                            // 92160 f32
    float*          bp1 = ws + 92736;                          // 92160 f32
    unsigned short* vb  = (unsigned short*)(ws + 184896);      // 40960 bf16
    unsigned short* Wo  = (unsigned short*)(ws + 205376);      // 1474560 bf16
    unsigned short* Wc  = (unsigned short*)(ws + 942656);      // 1474560 bf16
    unsigned short* xb  = (unsigned short*)(ws + 1679936);     // 2359296 bf16
    unsigned short* xT  = (unsigned short*)(ws + 2859584);     // 2359296 bf16
    // end: 4039232 f32 = 16.2 MB

    hipMemsetAsync(bar, 0, 576 * sizeof(unsigned int), stream);

    void* args[] = {(void*)&W, (void*)&x, (void*)&out, (void*)&Wo, (void*)&Wc,
                    (void*)&xb, (void*)&xT, (void*)&vb, (void*)&bp0, (void*)&bp1,
                    (void*)&bar};
    hipLaunchCooperativeKernel((const void*)k_all, dim3(GRID), dim3(256),
                               args, 0, stream);
}

// Round 6
// 250.983 us; speedup vs baseline: 2.1357x; 1.5577x over previous
//
#include <hip/hip_runtime.h>
#include <math.h>

#define IN_NUM 1152
#define IN_DIM 8
#define OUT_NUM 10
#define OUT_DIM 16
#define BATCH 256
#define KTOT 9216            // IN_DIM * IN_NUM; k = d*IN_NUM + i
#define WJ 147456            // 16 * 9216, per-j Wo/Wc stride
#define GRID 256

typedef __attribute__((ext_vector_type(8))) short short8;
typedef __attribute__((ext_vector_type(4))) short short4v;
typedef __attribute__((ext_vector_type(4))) float f32x4;

__device__ __forceinline__ unsigned short f2bf(float f) {
    unsigned int u = __builtin_bit_cast(unsigned int, f);
    u += 0x7FFF + ((u >> 16) & 1);          // RNE
    return (unsigned short)(u >> 16);
}
__device__ __forceinline__ float bf2f(unsigned short h) {
    unsigned int u = ((unsigned int)h) << 16;
    return __builtin_bit_cast(float, u);
}

// ---- two-level grid barrier, monotonic epochs, FENCE-FREE SPIN.
// Arrival: RELEASE RMW (one L2 writeback per block -> data reaches coherence pt).
// Tree + flag: RELAXED RMW (atomics act on the coherent copy regardless).
// Spin: RELAXED loads (NO buffer_inv per poll -- this was R5's 40us/barrier bug).
// Exit: one ACQUIRE agent fence per wave (single L2 inv before next phase reads).
// bar[l*32] l<16: leaf counters (128B apart); bar[512]: root; bar[544]: flag.
__device__ __forceinline__ void gbar(unsigned int* bar, unsigned int epoch) {
    __syncthreads();
    if (threadIdx.x == 0) {
        const int l = blockIdx.x & 15;
        unsigned int old = __hip_atomic_fetch_add(&bar[l * 32], 1u,
                               __ATOMIC_RELEASE, __HIP_MEMORY_SCOPE_AGENT);
        if ((old & 15u) == 15u) {            // 16th arrival at this leaf this epoch
            unsigned int r = __hip_atomic_fetch_add(&bar[512], 1u,
                               __ATOMIC_RELAXED, __HIP_MEMORY_SCOPE_AGENT);
            if ((r & 15u) == 15u)            // 16th leaf -> release
                __hip_atomic_fetch_add(&bar[544], 1u,
                               __ATOMIC_RELAXED, __HIP_MEMORY_SCOPE_AGENT);
        }
        while (__hip_atomic_load(&bar[544], __ATOMIC_RELAXED,
                                 __HIP_MEMORY_SCOPE_AGENT) < epoch)
            __builtin_amdgcn_s_sleep(4);     // ~256 cycles between relaxed polls
    }
    __syncthreads();
    __builtin_amdgcn_fence(__ATOMIC_ACQUIRE, "agent");   // one inv per wave
}

// ---- phase S: GEMM-s + squash. blocks [0,160) = (j, btile). 4 waves split K.
__device__ __forceinline__ void phase_S(const unsigned short* __restrict__ A,
                                        const unsigned short* __restrict__ xb,
                                        unsigned short* __restrict__ vb,
                                        float* __restrict__ out,
                                        float scale, int wout, float* LS) {
    if (blockIdx.x >= 160) return;
    const int j     = blockIdx.x >> 4;
    const int btile = blockIdx.x & 15;
    const int w    = threadIdx.x >> 6;
    const int lane = threadIdx.x & 63;
    const int row = lane & 15, kg = lane >> 4;

    const unsigned short* ap = A  + (size_t)j * WJ + row * KTOT + w * 2304 + kg * 8;
    const unsigned short* bp = xb + (size_t)(btile * 16 + row) * KTOT + w * 2304 + kg * 8;

    f32x4 acc0 = {0.f, 0.f, 0.f, 0.f}, acc1 = {0.f, 0.f, 0.f, 0.f};
    #pragma unroll 4
    for (int it = 0; it < 36; ++it) {        // 36 * 64 = 2304 k per wave, dual acc
        short8 a0 = *reinterpret_cast<const short8*>(ap);
        short8 b0 = *reinterpret_cast<const short8*>(bp);
        acc0 = __builtin_amdgcn_mfma_f32_16x16x32_bf16(a0, b0, acc0, 0, 0, 0);
        short8 a1 = *reinterpret_cast<const short8*>(ap + 32);
        short8 b1 = *reinterpret_cast<const short8*>(bp + 32);
        acc1 = __builtin_amdgcn_mfma_f32_16x16x32_bf16(a1, b1, acc1, 0, 0, 0);
        ap += 64; bp += 64;
    }
    f32x4 acc = acc0 + acc1;
    // D: col(lane&15) -> b, row kg*4+r -> o.  Sred[w][o][b] = LS[w*256+o*16+b]
    #pragma unroll
    for (int r = 0; r < 4; ++r) LS[w * 256 + (kg * 4 + r) * 16 + row] = acc[r];
    __syncthreads();

    const int o = threadIdx.x >> 4, b = threadIdx.x & 15;
    float sum = LS[0 * 256 + o * 16 + b] + LS[1 * 256 + o * 16 + b]
              + LS[2 * 256 + o * 16 + b] + LS[3 * 256 + o * 16 + b];
    __syncthreads();
    LS[o * 16 + b] = sum;                    // own slot
    __syncthreads();
    float m2r = 0.f;
    #pragma unroll
    for (int oo = 0; oo < 16; ++oo) { const float q = LS[oo * 16 + b]; m2r += q * q; }
    const float m2 = m2r * scale * scale;
    const float f  = sqrtf(m2) / (1.0f + m2);
    vb[(size_t)j * OUT_DIM * BATCH + o * BATCH + btile * 16 + b] = f2bf(sum * scale * f);
    if (wout) {
        if (o == 0) LS[1024 + b] = f;        // fs[b]
        __syncthreads();
        const int b2 = threadIdx.x >> 4, o2 = threadIdx.x & 15;
        out[((size_t)j * BATCH + btile * 16 + b2) * OUT_DIM + o2] =
            LS[o2 * 16 + b2] * scale * LS[1024 + b2];   // coalesced f32
    }
}

// ---- phase G: GEMM-G + b-partials. 5760 wave units grid-strided over GRID*4.
__device__ __forceinline__ void phase_G(const unsigned short* __restrict__ xT,
                                        const unsigned short* __restrict__ vb,
                                        const unsigned short* __restrict__ Wo,
                                        float* __restrict__ bpd) {
    const int w    = threadIdx.x >> 6;
    const int lane = threadIdx.x & 63;
    const int rc = lane & 15, kg = lane >> 4;
    for (int base = 0; base < 5760; base += GRID * 4) {
        const int wid = base + blockIdx.x * 4 + w;
        if (wid >= 5760) break;
        const int j  = wid % 10;
        const int kt = wid / 10;             // < 576

        const unsigned short* ap = xT + (size_t)(kt * 16 + rc) * BATCH + kg * 8;
        const unsigned short* vp = vb + (size_t)j * OUT_DIM * BATCH + rc * BATCH + kg * 8;

        f32x4 acc0 = {0.f, 0.f, 0.f, 0.f}, acc1 = {0.f, 0.f, 0.f, 0.f};
        #pragma unroll
        for (int bb = 0; bb < 4; ++bb) {     // 4 * 64 = 256 = BATCH, dual acc
            short8 a0 = *reinterpret_cast<const short8*>(ap + bb * 64);
            short8 b0 = *reinterpret_cast<const short8*>(vp + bb * 64);
            acc0 = __builtin_amdgcn_mfma_f32_16x16x32_bf16(a0, b0, acc0, 0, 0, 0);
            short8 a1 = *reinterpret_cast<const short8*>(ap + bb * 64 + 32);
            short8 b1 = *reinterpret_cast<const short8*>(vp + bb * 64 + 32);
            acc1 = __builtin_amdgcn_mfma_f32_16x16x32_bf16(a1, b1, acc1, 0, 0, 0);
        }
        f32x4 acc = acc0 + acc1;
        // lane(rc,kg) holds G[k = kt*16 + kg*4 + r][o = rc]
        const int kbase = kt * 16 + kg * 4;
        short4v w4 = *reinterpret_cast<const short4v*>(
            Wo + (size_t)j * WJ + rc * KTOT + kbase);
        float p[4];
        #pragma unroll
        for (int r = 0; r < 4; ++r) p[r] = acc[r] * bf2f((unsigned short)w4[r]);
        #pragma unroll
        for (int m = 1; m < 16; m <<= 1) {
            #pragma unroll
            for (int r = 0; r < 4; ++r) p[r] += __shfl_xor(p[r], m);
        }
        if (rc == 0) {
            float4 v4 = make_float4(p[0], p[1], p[2], p[3]);
            *reinterpret_cast<float4*>(bpd + (size_t)j * KTOT + kbase) = v4;
        }
    }
}

// ---- phase CW: fused softmax(from bp partials) + Wc = c * Wo. blocks [0,180).
__device__ __forceinline__ void phase_CW(const float* __restrict__ bp0,
                                         const float* __restrict__ bp1,
                                         const unsigned short* __restrict__ Wo,
                                         unsigned short* __restrict__ Wc,
                                         float* LS) {
    if (blockIdx.x >= 180) return;
    const int j0 = blockIdx.x / 18;
    const int i0 = (blockIdx.x % 18) * 64;
    const int t = threadIdx.x;
    if (t < 64) {
        const int i = i0 + t;
        float lg[OUT_NUM];
        float m = -INFINITY;
        #pragma unroll
        for (int j = 0; j < OUT_NUM; ++j) {
            float s = 0.f;
            #pragma unroll
            for (int d = 0; d < IN_DIM; ++d) {
                s += bp0[(size_t)j * KTOT + d * IN_NUM + i];
                if (bp1) s += bp1[(size_t)j * KTOT + d * IN_NUM + i];
            }
            lg[j] = s * (1.0f / BATCH);
            m = fmaxf(m, lg[j]);
        }
        float den = 0.f;
        #pragma unroll
        for (int j = 0; j < OUT_NUM; ++j) den += expf(lg[j] - m);
        LS[t] = expf(lg[j0] - m) / den;      // cs[il]
    }
    __syncthreads();
    #pragma unroll
    for (int q = 0; q < 4; ++q) {
        const int ev = t + 256 * q;          // vector-of-8 index, 1024 total
        const int od = ev >> 3;              // 0..127
        const int il = (ev & 7) * 8;
        const int o = od >> 3, d = od & 7;
        const size_t idx = (size_t)j0 * WJ + o * KTOT + d * IN_NUM + i0 + il;
        short8 wv = *reinterpret_cast<const short8*>(Wo + idx);
        unsigned short ov[8];
        #pragma unroll
        for (int e = 0; e < 8; ++e)
            ov[e] = f2bf(bf2f((unsigned short)wv[e]) * LS[il + e]);
        *reinterpret_cast<short8*>(Wc + idx) = *reinterpret_cast<const short8*>(ov);
    }
}

// ---------------------------------------------------------------------------
__global__ __launch_bounds__(256, 2) void k_all(const float* __restrict__ W,
                                                const float* __restrict__ x,
                                                float* __restrict__ out,
                                                unsigned short* __restrict__ Wo,
                                                unsigned short* __restrict__ Wc,
                                                unsigned short* __restrict__ xb,
                                                unsigned short* __restrict__ xT,
                                                unsigned short* __restrict__ vb,
                                                float* __restrict__ bp0,
                                                float* __restrict__ bp1,
                                                unsigned int* bar) {
    __shared__ float LS[8320];               // 33.3 KB, unioned across phases
    const int t = threadIdx.x;

    // ---- P: prep. units [0,180): W -> Wo bf16; [180,756): x -> xb, xT bf16
    for (int unit = blockIdx.x; unit < 756; unit += GRID) {
        if (unit < 180) {
            const int j  = unit / 18;
            const int i0 = (unit % 18) * 64;
            #pragma unroll 4
            for (int st = 0; st < 32; ++st) {
                const int il = st * 2 + (t >> 7);
                const int od = t & 127;
                LS[il * 130 + od] = W[(size_t)(i0 + il) * 1280 + j * 128 + od];
            }
            __syncthreads();
            #pragma unroll 4
            for (int st = 0; st < 32; ++st) {
                const int od = st * 4 + (t >> 6);
                const int il = t & 63;
                const int o = od >> 3, d = od & 7;
                Wo[(size_t)j * WJ + o * KTOT + d * IN_NUM + i0 + il] = f2bf(LS[il * 130 + od]);
            }
        } else {
            const int bx = unit - 180;
            const int k0 = (bx >> 2) * 64;
            const int b0 = (bx & 3) * 64;
            #pragma unroll 4
            for (int st = 0; st < 16; ++st) {
                const int bl = st * 4 + (t >> 6);
                const int kl = t & 63;
                const float f = x[(size_t)(b0 + bl) * KTOT + k0 + kl];
                LS[kl * 65 + bl] = f;
                xb[(size_t)(b0 + bl) * KTOT + k0 + kl] = f2bf(f);
            }
            __syncthreads();
            #pragma unroll 4
            for (int st = 0; st < 16; ++st) {
                const int kl = st * 4 + (t >> 6);
                const int bl = t & 63;
                xT[(size_t)(k0 + kl) * BATCH + b0 + bl] = f2bf(LS[kl * 65 + bl]);
            }
        }
        __syncthreads();
    }
    gbar(bar, 1);
    // iter 0 (c uniform 0.1 folded into squash scale)
    phase_S(Wo, xb, vb, out, 0.1f, 0, LS);
    gbar(bar, 2);
    phase_G(xT, vb, Wo, bp0);
    gbar(bar, 3);
    // iter 1
    phase_CW(bp0, nullptr, Wo, Wc, LS);
    gbar(bar, 4);
    phase_S(Wc, xb, vb, out, 1.0f, 0, LS);
    gbar(bar, 5);
    phase_G(xT, vb, Wo, bp1);
    gbar(bar, 6);
    // iter 2 (final)
    phase_CW(bp0, bp1, Wo, Wc, LS);
    gbar(bar, 7);
    phase_S(Wc, xb, vb, out, 1.0f, 1, LS);
}

// ---------------------------------------------------------------------------
extern "C" void kernel_launch(void* const* d_in, const int* in_sizes, int n_in,
                              void* d_out, int out_size, void* d_ws, size_t ws_size,
                              hipStream_t stream) {
    const float* x = (const float*)d_in[0];   // [256][8][1152]
    const float* W = (const float*)d_in[1];   // [1152][10][16][8]
    float* out = (float*)d_out;               // [10][256][16]
    float* ws = (float*)d_ws;

    unsigned int*   bar = (unsigned int*)ws;                   // 576 u32 (barrier)
    float*          bp0 = ws + 576;                            // 92160 f32
    float*          bp1 = ws + 92736;                          // 92160 f32
    unsigned short* vb  = (unsigned short*)(ws + 184896);      // 40960 bf16
    unsigned short* Wo  = (unsigned short*)(ws + 205376);      // 1474560 bf16
    unsigned short* Wc  = (unsigned short*)(ws + 942656);      // 1474560 bf16
    unsigned short* xb  = (unsigned short*)(ws + 1679936);     // 2359296 bf16
    unsigned short* xT  = (unsigned short*)(ws + 2859584);     // 2359296 bf16
    // end: 4039232 f32 = 16.2 MB

    hipMemsetAsync(bar, 0, 576 * sizeof(unsigned int), stream);

    void* args[] = {(void*)&W, (void*)&x, (void*)&out, (void*)&Wo, (void*)&Wc,
                    (void*)&xb, (void*)&xT, (void*)&vb, (void*)&bp0, (void*)&bp1,
                    (void*)&bar};
    hipLaunchCooperativeKernel((const void*)k_all, dim3(GRID), dim3(256),
                               args, 0, stream);
}

// Round 7
// 170.594 us; speedup vs baseline: 3.1422x; 1.4712x over previous
//
#include <hip/hip_runtime.h>
#include <math.h>

#define IN_NUM 1152
#define IN_DIM 8
#define OUT_NUM 10
#define OUT_DIM 16
#define BATCH 256
#define KTOT 9216            // IN_DIM * IN_NUM; k = d*IN_NUM + i
#define WJ 147456            // 16 * 9216, per-j Wo/Wc stride
#define GRID 512

typedef __attribute__((ext_vector_type(8))) short short8;
typedef __attribute__((ext_vector_type(4))) short short4v;
typedef __attribute__((ext_vector_type(4))) float f32x4;

__device__ __forceinline__ unsigned short f2bf(float f) {
    unsigned int u = __builtin_bit_cast(unsigned int, f);
    u += 0x7FFF + ((u >> 16) & 1);          // RNE
    return (unsigned short)(u >> 16);
}
__device__ __forceinline__ float bf2f(unsigned short h) {
    unsigned int u = ((unsigned int)h) << 16;
    return __builtin_bit_cast(float, u);
}

// Device-scope write-through stores (sc1): bypass/no-allocate L2, land at the
// coherence point. Consumers on other XCDs read with NORMAL cached loads --
// safe because every such address is written exactly once per launch, before
// any read (write-once discipline; Wc/vb are double-buffered to guarantee it).
__device__ __forceinline__ void st_dev_u32(unsigned int* p, unsigned int v) {
    __hip_atomic_store(p, v, __ATOMIC_RELAXED, __HIP_MEMORY_SCOPE_AGENT);
}
__device__ __forceinline__ void st_dev_f32(float* p, float v) {
    __hip_atomic_store(p, v, __ATOMIC_RELAXED, __HIP_MEMORY_SCOPE_AGENT);
}

// ---- two-level grid barrier: NO release, NO acquire, NO cache maintenance.
// __syncthreads drains vmcnt(0) (sc1 stores complete at coherence point);
// arrival/tree/flag/spin are all RELAXED agent atomics (operate on the
// coherent copy; no buffer_inv / buffer_wbl2 ever emitted).
// bar[l*32] l<16: leaves (128B apart, 32 blocks each); bar[512]: root; bar[544]: flag.
__device__ __forceinline__ void gbar(unsigned int* bar, unsigned int epoch) {
    asm volatile("s_waitcnt vmcnt(0)" ::: "memory");
    __syncthreads();
    if (threadIdx.x == 0) {
        const int l = blockIdx.x & 15;
        unsigned int old = __hip_atomic_fetch_add(&bar[l * 32], 1u,
                               __ATOMIC_RELAXED, __HIP_MEMORY_SCOPE_AGENT);
        if ((old & 31u) == 31u) {            // 32nd arrival at this leaf this epoch
            unsigned int r = __hip_atomic_fetch_add(&bar[512], 1u,
                               __ATOMIC_RELAXED, __HIP_MEMORY_SCOPE_AGENT);
            if ((r & 15u) == 15u)            // 16th leaf -> release
                __hip_atomic_fetch_add(&bar[544], 1u,
                               __ATOMIC_RELAXED, __HIP_MEMORY_SCOPE_AGENT);
        }
        while (__hip_atomic_load(&bar[544], __ATOMIC_RELAXED,
                                 __HIP_MEMORY_SCOPE_AGENT) < epoch)
            __builtin_amdgcn_s_sleep(4);     // ~256 cycles between polls
    }
    __syncthreads();
}

// ---- phase S: GEMM-s + squash. blocks [0,160) = (j, btile). 4 waves split K.
// Reads A (Wo/WcA/WcB) and xb with normal cached loads; writes vb via sc1.
__device__ __forceinline__ void phase_S(const unsigned short* __restrict__ A,
                                        const unsigned short* __restrict__ xb,
                                        unsigned short* __restrict__ vb,
                                        float* __restrict__ out,
                                        float scale, int wout, float* LS) {
    if (blockIdx.x >= 160) return;
    const int j     = blockIdx.x >> 4;
    const int btile = blockIdx.x & 15;
    const int w    = threadIdx.x >> 6;
    const int lane = threadIdx.x & 63;
    const int row = lane & 15, kg = lane >> 4;
    const int t = threadIdx.x;

    const unsigned short* ap = A  + (size_t)j * WJ + row * KTOT + w * 2304 + kg * 8;
    const unsigned short* bp = xb + (size_t)(btile * 16 + row) * KTOT + w * 2304 + kg * 8;

    f32x4 acc0 = {0.f, 0.f, 0.f, 0.f}, acc1 = {0.f, 0.f, 0.f, 0.f};
    #pragma unroll 4
    for (int it = 0; it < 36; ++it) {        // 36 * 64 = 2304 k per wave, dual acc
        short8 a0 = *reinterpret_cast<const short8*>(ap);
        short8 b0 = *reinterpret_cast<const short8*>(bp);
        acc0 = __builtin_amdgcn_mfma_f32_16x16x32_bf16(a0, b0, acc0, 0, 0, 0);
        short8 a1 = *reinterpret_cast<const short8*>(ap + 32);
        short8 b1 = *reinterpret_cast<const short8*>(bp + 32);
        acc1 = __builtin_amdgcn_mfma_f32_16x16x32_bf16(a1, b1, acc1, 0, 0, 0);
        ap += 64; bp += 64;
    }
    f32x4 acc = acc0 + acc1;
    // D: col(lane&15) -> b, row kg*4+r -> o.  Sred[w][o][b] = LS[w*256+o*16+b]
    #pragma unroll
    for (int r = 0; r < 4; ++r) LS[w * 256 + (kg * 4 + r) * 16 + row] = acc[r];
    __syncthreads();

    const int o = t >> 4, b = t & 15;
    float sum = LS[0 * 256 + o * 16 + b] + LS[1 * 256 + o * 16 + b]
              + LS[2 * 256 + o * 16 + b] + LS[3 * 256 + o * 16 + b];
    __syncthreads();
    LS[o * 16 + b] = sum;                    // own slot
    __syncthreads();
    if (t < 16) {                            // b = t: squash factor per column
        float m2r = 0.f;
        #pragma unroll
        for (int oo = 0; oo < 16; ++oo) { const float q = LS[oo * 16 + t]; m2r += q * q; }
        const float m2 = m2r * scale * scale;
        LS[256 + t] = sqrtf(m2) / (1.0f + m2);
    }
    __syncthreads();
    if (wout) {
        const int b2 = t >> 4, o2 = t & 15;
        out[((size_t)j * BATCH + btile * 16 + b2) * OUT_DIM + o2] =
            LS[o2 * 16 + b2] * scale * LS[256 + b2];    // plain store, kernel-end flush
    } else if (t < 128) {                    // pack 2 bf16 -> one sc1 u32 store
        const int oo = t >> 3, b0p = (t & 7) * 2;
        const unsigned int lo = f2bf(LS[oo * 16 + b0p]     * scale * LS[256 + b0p]);
        const unsigned int hi = f2bf(LS[oo * 16 + b0p + 1] * scale * LS[256 + b0p + 1]);
        st_dev_u32((unsigned int*)(vb + (size_t)j * OUT_DIM * BATCH + oo * BATCH
                                   + btile * 16 + b0p), lo | (hi << 16));
    }
}

// ---- phase G: GEMM-G + b-partials. 5760 wave units grid-strided; bp via sc1.
__device__ __forceinline__ void phase_G(const unsigned short* __restrict__ xT,
                                        const unsigned short* __restrict__ vb,
                                        const unsigned short* __restrict__ Wo,
                                        float* __restrict__ bpd) {
    const int w    = threadIdx.x >> 6;
    const int lane = threadIdx.x & 63;
    const int rc = lane & 15, kg = lane >> 4;
    for (int base = 0; base < 5760; base += GRID * 4) {
        const int wid = base + blockIdx.x * 4 + w;
        if (wid >= 5760) break;
        const int j  = wid % 10;
        const int kt = wid / 10;             // < 576

        const unsigned short* ap = xT + (size_t)(kt * 16 + rc) * BATCH + kg * 8;
        const unsigned short* vp = vb + (size_t)j * OUT_DIM * BATCH + rc * BATCH + kg * 8;

        f32x4 acc0 = {0.f, 0.f, 0.f, 0.f}, acc1 = {0.f, 0.f, 0.f, 0.f};
        #pragma unroll
        for (int bb = 0; bb < 4; ++bb) {     // 4 * 64 = 256 = BATCH, dual acc
            short8 a0 = *reinterpret_cast<const short8*>(ap + bb * 64);
            short8 b0 = *reinterpret_cast<const short8*>(vp + bb * 64);
            acc0 = __builtin_amdgcn_mfma_f32_16x16x32_bf16(a0, b0, acc0, 0, 0, 0);
            short8 a1 = *reinterpret_cast<const short8*>(ap + bb * 64 + 32);
            short8 b1 = *reinterpret_cast<const short8*>(vp + bb * 64 + 32);
            acc1 = __builtin_amdgcn_mfma_f32_16x16x32_bf16(a1, b1, acc1, 0, 0, 0);
        }
        f32x4 acc = acc0 + acc1;
        // lane(rc,kg) holds G[k = kt*16 + kg*4 + r][o = rc]
        const int kbase = kt * 16 + kg * 4;
        short4v w4 = *reinterpret_cast<const short4v*>(
            Wo + (size_t)j * WJ + rc * KTOT + kbase);
        float p[4];
        #pragma unroll
        for (int r = 0; r < 4; ++r) p[r] = acc[r] * bf2f((unsigned short)w4[r]);
        #pragma unroll
        for (int m = 1; m < 16; m <<= 1) {
            #pragma unroll
            for (int r = 0; r < 4; ++r) p[r] += __shfl_xor(p[r], m);
        }
        if (rc == 0) {
            #pragma unroll
            for (int r = 0; r < 4; ++r)
                st_dev_f32(bpd + (size_t)j * KTOT + kbase + r, p[r]);
        }
    }
}

// ---- phase CW: fused softmax(from bp partials) + Wc = c * Wo. blocks [0,180).
// Reads bp0/bp1/Wo cached; writes Wc via sc1 (paired u32).
__device__ __forceinline__ void phase_CW(const float* __restrict__ bp0,
                                         const float* __restrict__ bp1,
                                         const unsigned short* __restrict__ Wo,
                                         unsigned short* __restrict__ Wc,
                                         float* LS) {
    if (blockIdx.x >= 180) return;
    const int j0 = blockIdx.x / 18;
    const int i0 = (blockIdx.x % 18) * 64;
    const int t = threadIdx.x;
    if (t < 64) {
        const int i = i0 + t;
        float lg[OUT_NUM];
        float m = -INFINITY;
        #pragma unroll
        for (int j = 0; j < OUT_NUM; ++j) {
            float s = 0.f;
            #pragma unroll
            for (int d = 0; d < IN_DIM; ++d) {
                s += bp0[(size_t)j * KTOT + d * IN_NUM + i];
                if (bp1) s += bp1[(size_t)j * KTOT + d * IN_NUM + i];
            }
            lg[j] = s * (1.0f / BATCH);
            m = fmaxf(m, lg[j]);
        }
        float den = 0.f;
        #pragma unroll
        for (int j = 0; j < OUT_NUM; ++j) den += expf(lg[j] - m);
        LS[t] = expf(lg[j0] - m) / den;      // cs[il]
    }
    __syncthreads();
    #pragma unroll
    for (int q = 0; q < 4; ++q) {
        const int ev = t + 256 * q;          // vector-of-8 index, 1024 total
        const int od = ev >> 3;              // 0..127
        const int il = (ev & 7) * 8;
        const int o = od >> 3, d = od & 7;
        const size_t idx = (size_t)j0 * WJ + o * KTOT + d * IN_NUM + i0 + il;
        short8 wv = *reinterpret_cast<const short8*>(Wo + idx);
        unsigned int ov[4];
        #pragma unroll
        for (int e = 0; e < 4; ++e) {
            const unsigned int lo = f2bf(bf2f((unsigned short)wv[2 * e])     * LS[il + 2 * e]);
            const unsigned int hi = f2bf(bf2f((unsigned short)wv[2 * e + 1]) * LS[il + 2 * e + 1]);
            ov[e] = lo | (hi << 16);
        }
        unsigned int* wp = (unsigned int*)(Wc + idx);
        #pragma unroll
        for (int e = 0; e < 4; ++e) st_dev_u32(wp + e, ov[e]);
    }
}

// ---------------------------------------------------------------------------
__global__ __launch_bounds__(256, 2) void k_all(const float* __restrict__ W,
                                                const float* __restrict__ x,
                                                float* __restrict__ out,
                                                unsigned short* __restrict__ Wo,
                                                unsigned short* __restrict__ WcA,
                                                unsigned short* __restrict__ WcB,
                                                unsigned short* __restrict__ xb,
                                                unsigned short* __restrict__ xT,
                                                unsigned short* __restrict__ vb0,
                                                unsigned short* __restrict__ vb1,
                                                float* __restrict__ bp0,
                                                float* __restrict__ bp1,
                                                unsigned int* bar) {
    __shared__ float LS[8320];               // 33.3 KB, unioned across phases
    const int t = threadIdx.x;

    // ---- P: prep. units [0,180): W -> Wo bf16; [180,756): x -> xb, xT bf16.
    // Reads cached; ALL output stores sc1 (write-through) -> no fence needed.
    for (int unit = blockIdx.x; unit < 756; unit += GRID) {
        if (unit < 180) {
            const int j  = unit / 18;
            const int i0 = (unit % 18) * 64;
            #pragma unroll 4
            for (int st = 0; st < 32; ++st) {
                const int il = st * 2 + (t >> 7);
                const int od = t & 127;
                LS[il * 130 + od] = W[(size_t)(i0 + il) * 1280 + j * 128 + od];
            }
            __syncthreads();
            #pragma unroll 4
            for (int q = 0; q < 16; ++q) {   // 4096 u32 = 128 od x 32 il-pairs
                const int u   = q * 256 + t;
                const int od  = u >> 5;
                const int ilp = (u & 31) * 2;
                const int o = od >> 3, d = od & 7;
                const unsigned int lo = f2bf(LS[ilp * 130 + od]);
                const unsigned int hi = f2bf(LS[(ilp + 1) * 130 + od]);
                st_dev_u32((unsigned int*)(Wo + (size_t)j * WJ + o * KTOT
                                           + d * IN_NUM + i0 + ilp), lo | (hi << 16));
            }
        } else {
            const int bx = unit - 180;
            const int k0 = (bx >> 2) * 64;
            const int b0 = (bx & 3) * 64;
            #pragma unroll 4
            for (int st = 0; st < 16; ++st) {
                const int bl = st * 4 + (t >> 6);
                const int kl = t & 63;
                LS[kl * 65 + bl] = x[(size_t)(b0 + bl) * KTOT + k0 + kl];  // coalesced
            }
            __syncthreads();
            #pragma unroll 4
            for (int q = 0; q < 8; ++q) {    // xb: 2048 u32 = 64 bl x 32 kl-pairs
                const int u   = q * 256 + t;
                const int bl  = u >> 5;
                const int klp = (u & 31) * 2;
                const unsigned int lo = f2bf(LS[klp * 65 + bl]);
                const unsigned int hi = f2bf(LS[(klp + 1) * 65 + bl]);
                st_dev_u32((unsigned int*)(xb + (size_t)(b0 + bl) * KTOT + k0 + klp),
                           lo | (hi << 16));
            }
            #pragma unroll 4
            for (int q = 0; q < 8; ++q) {    // xT: 2048 u32 = 64 kl x 32 bl-pairs
                const int u   = q * 256 + t;
                const int kl  = u >> 5;
                const int blp = (u & 31) * 2;
                const unsigned int lo = f2bf(LS[kl * 65 + blp]);
                const unsigned int hi = f2bf(LS[kl * 65 + blp + 1]);
                st_dev_u32((unsigned int*)(xT + (size_t)(k0 + kl) * BATCH + b0 + blp),
                           lo | (hi << 16));
            }
        }
        __syncthreads();
    }
    gbar(bar, 1);
    // iter 0 (c uniform 0.1 folded into squash scale)
    phase_S(Wo, xb, vb0, out, 0.1f, 0, LS);
    gbar(bar, 2);
    phase_G(xT, vb0, Wo, bp0);
    gbar(bar, 3);
    // iter 1
    phase_CW(bp0, nullptr, Wo, WcA, LS);
    gbar(bar, 4);
    phase_S(WcA, xb, vb1, out, 1.0f, 0, LS);
    gbar(bar, 5);
    phase_G(xT, vb1, Wo, bp1);
    gbar(bar, 6);
    // iter 2 (final)
    phase_CW(bp0, bp1, Wo, WcB, LS);
    gbar(bar, 7);
    phase_S(WcB, xb, nullptr, out, 1.0f, 1, LS);
}

// ---------------------------------------------------------------------------
extern "C" void kernel_launch(void* const* d_in, const int* in_sizes, int n_in,
                              void* d_out, int out_size, void* d_ws, size_t ws_size,
                              hipStream_t stream) {
    const float* x = (const float*)d_in[0];   // [256][8][1152]
    const float* W = (const float*)d_in[1];   // [1152][10][16][8]
    float* out = (float*)d_out;               // [10][256][16]
    float* ws = (float*)d_ws;

    unsigned int*   bar = (unsigned int*)ws;                   // 576 u32
    float*          bp0 = ws + 576;                            // 92160 f32
    float*          bp1 = ws + 92736;                          // 92160 f32
    unsigned short* vb0 = (unsigned short*)(ws + 184896);      // 40960 bf16
    unsigned short* vb1 = (unsigned short*)(ws + 205376);      // 40960 bf16
    unsigned short* Wo  = (unsigned short*)(ws + 225856);      // 1474560 bf16
    unsigned short* WcA = (unsigned short*)(ws + 963136);      // 1474560 bf16
    unsigned short* WcB = (unsigned short*)(ws + 1700416);     // 1474560 bf16
    unsigned short* xb  = (unsigned short*)(ws + 2437696);     // 2359296 bf16
    unsigned short* xT  = (unsigned short*)(ws + 3617344);     // 2359296 bf16
    // end: 4796992 f32 = 19.2 MB

    hipMemsetAsync(bar, 0, 576 * sizeof(unsigned int), stream);

    void* args[] = {(void*)&W, (void*)&x, (void*)&out, (void*)&Wo, (void*)&WcA,
                    (void*)&WcB, (void*)&xb, (void*)&xT, (void*)&vb0, (void*)&vb1,
                    (void*)&bp0, (void*)&bp1, (void*)&bar};
    hipLaunchCooperativeKernel((const void*)k_all, dim3(GRID), dim3(256),
                               args, 0, stream);
}